// Round 5
// baseline (386.099 us; speedup 1.0000x reference)
//
#include <hip/hip_runtime.h>

// SNN layer: out[b,n] = clip( sum_m pre[b,m]*W[m,n] + cst[b,n] - thr[b,n], 0, 0.9 )
// B=8, M=8192, N=8192 fp32. Memory-bound: one pass over W = 268 MB.
//
// R5: fully-contiguous W streams. Each stage-1 block owns a contiguous 1 MB
// slab of W (32 rows x 8192 cols) and accumulates those rows' contribution to
// ALL (b,n) outputs in registers (128 VGPR acc/thread), sweeping the slab
// front-to-back like a memcpy. Thread t owns cols {4t + 2048j}, so every
// wave-load is a unit-stride 1 KB burst. Partials [256][8][8192] (67 MB, ws),
// reduced by stage 2 (L3-hot) with fused epilogue.

constexpr int Mdim = 8192;
constexpr int Ndim = 8192;
constexpr int Bdim = 8;
constexpr int NBLK = 256;              // stage-1 blocks = row slabs
constexpr int SLAB = Mdim / NBLK;      // 32 rows per slab
constexpr float CAP = 0.9f;

__global__ __launch_bounds__(512, 2) void snn_stage1(
    const float* __restrict__ pre,   // [B, M]
    const float* __restrict__ W,     // [M, N]
    float* __restrict__ part)        // [NBLK, B, N]
{
    __shared__ float lds_pre[Bdim * SLAB];   // 1 KB: [b][row-in-slab]

    const int t  = threadIdx.x;              // 0..511
    const int k  = blockIdx.x;               // slab id
    const int r0 = k * SLAB;
    const int c0 = t * 4;                    // col within 2048-group

    if (t < Bdim * SLAB) {
        int b = t >> 5, j = t & (SLAB - 1);
        lds_pre[t] = pre[b * Mdim + r0 + j];
    }

    float4 acc[Bdim][4];
#pragma unroll
    for (int b = 0; b < Bdim; ++b)
#pragma unroll
        for (int j = 0; j < 4; ++j) acc[b][j] = make_float4(0.f, 0.f, 0.f, 0.f);

    const float* Wb = W + (size_t)r0 * Ndim + c0;

    auto loadW = [&](float4* w, int rr) {
        const float* p = Wb + (size_t)rr * Ndim;
#pragma unroll
        for (int j = 0; j < 4; ++j)
            w[j] = *reinterpret_cast<const float4*>(p + 2048 * j);
    };

    auto compute = [&](const float4* w, int rr) {
#pragma unroll
        for (int b = 0; b < Bdim; ++b) {
            const float p = lds_pre[b * SLAB + rr];   // wave-uniform broadcast
#pragma unroll
            for (int j = 0; j < 4; ++j) {
                float4 a = acc[b][j];
                a.x = fmaf(p, w[j].x, a.x);
                a.y = fmaf(p, w[j].y, a.y);
                a.z = fmaf(p, w[j].z, a.z);
                a.w = fmaf(p, w[j].w, a.w);
                acc[b][j] = a;
            }
        }
    };

    // 2-deep pipeline over the 32 sequential rows of the slab.
    float4 wA[4], wB[4];
    loadW(wA, 0);
    __syncthreads();

    for (int rr = 0; rr < SLAB; rr += 2) {
        loadW(wB, rr + 1);
        compute(wA, rr);
        if (rr + 2 < SLAB) loadW(wA, rr + 2);
        compute(wB, rr + 1);
    }

    float* ps = part + (size_t)k * (Bdim * Ndim) + c0;
#pragma unroll
    for (int b = 0; b < Bdim; ++b)
#pragma unroll
        for (int j = 0; j < 4; ++j)
            *reinterpret_cast<float4*>(ps + (size_t)b * Ndim + 2048 * j) = acc[b][j];
}

__global__ __launch_bounds__(256, 4) void snn_stage2(
    const float* __restrict__ part,  // [NBLK, B*N]
    const float* __restrict__ thr,   // [B, N]
    const float* __restrict__ cst,   // [B, N]
    float* __restrict__ out)         // [B, N]
{
    const int bid = blockIdx.x;
    const int i = bid * 256 + threadIdx.x;   // 0 .. B*N-1
    float s = 0.f;
#pragma unroll 8
    for (int k = 0; k < NBLK; ++k) {
        int kk = (k + bid) & (NBLK - 1);     // spread k-slab pressure
        s += part[(size_t)kk * (Bdim * Ndim) + i];
    }
    float x = s + cst[i] - thr[i];
    x = fminf(fmaxf(x, 0.f), CAP);
    out[i] = x;
}

extern "C" void kernel_launch(void* const* d_in, const int* in_sizes, int n_in,
                              void* d_out, int out_size, void* d_ws, size_t ws_size,
                              hipStream_t stream) {
    const float* pre = (const float*)d_in[0];   // [8,1,8192]
    const float* W   = (const float*)d_in[1];   // [8192,8192]
    const float* thr = (const float*)d_in[2];   // [8,1,8192]
    const float* cst = (const float*)d_in[3];   // [8,1,8192]
    float* out  = (float*)d_out;                // [8,1,8192]
    float* part = (float*)d_ws;                 // 67.1 MB partials

    hipLaunchKernelGGL(snn_stage1, dim3(NBLK), dim3(512), 0, stream, pre, W, part);
    hipLaunchKernelGGL(snn_stage2, dim3((Bdim * Ndim) / 256), dim3(256), 0, stream,
                       part, thr, cst, out);
}